// Round 18
// baseline (200.621 us; speedup 1.0000x reference)
//
#include <hip/hip_runtime.h>

#define B_DIM 4
#define P_DIM 2048
#define C_DIM 1024
#define H_CNT 16
#define D_HEAD 64
#define M_DIM 8192   // B*P
#define K_DIM 1024

typedef __attribute__((ext_vector_type(4))) float  f32x4;
typedef __attribute__((ext_vector_type(8))) __bf16 bf16x8;
typedef __attribute__((ext_vector_type(4))) __bf16 bf16x4;
typedef __attribute__((ext_vector_type(4))) short  s16x4;
typedef __attribute__((ext_vector_type(8))) short  s16x8;

static __device__ __forceinline__ short f2bf(float f) {
    unsigned u = __float_as_uint(f);
    u += 0x7fff + ((u >> 16) & 1);   // RNE
    return (short)(u >> 16);
}

#define GLDS16(src, dst) __builtin_amdgcn_global_load_lds( \
    (__attribute__((address_space(1))) void*)(void*)(src), \
    (__attribute__((address_space(3))) void*)(void*)(dst), 16, 0, 0)

// ---------------- f32 -> bf16 elementwise (x) ----------------
__global__ __launch_bounds__(256) void cvt_f32_bf16(const float* __restrict__ in,
                                                    short* __restrict__ out) {
    size_t i = ((size_t)blockIdx.x * 256 + threadIdx.x) * 4;
    f32x4 v = *(const f32x4*)(in + i);
    s16x4 o;
    o[0] = f2bf(v[0]); o[1] = f2bf(v[1]); o[2] = f2bf(v[2]); o[3] = f2bf(v[3]);
    *(s16x4*)(out + i) = o;
}

// ---------------- all four W [K][N] f32 -> W^T [N][K] bf16, one dispatch ----------------
__global__ __launch_bounds__(256) void wtrans_all(const float* __restrict__ W0,
                                                  const float* __restrict__ W1,
                                                  const float* __restrict__ W2,
                                                  const float* __restrict__ W3,
                                                  short* __restrict__ WT) {
    __shared__ float t[32][33];
    const int z = blockIdx.z;
    const float* W = z == 0 ? W0 : z == 1 ? W1 : z == 2 ? W2 : W3;
    short* dst = WT + (size_t)z * C_DIM * C_DIM;
    const int k0 = blockIdx.y * 32, n0 = blockIdx.x * 32;
    const int tx = threadIdx.x & 31, ty = threadIdx.x >> 5;   // ty 0..7
#pragma unroll
    for (int j = 0; j < 4; ++j)
        t[ty + j * 8][tx] = W[(size_t)(k0 + ty + j * 8) * C_DIM + n0 + tx];
    __syncthreads();
#pragma unroll
    for (int j = 0; j < 4; ++j)
        dst[(size_t)(n0 + ty + j * 8) * C_DIM + k0 + tx] = f2bf(t[tx][ty + j * 8]);
}

// ---------------- 8-phase GEMM template (T3+T4+T5, verified R17) ----------------
// A bf16 [M=8192][K=1024]; BT bf16 [N][K]. 512 threads = 8 waves (2M x 4N), BM=256,
// BK=64, LDS A-dbuf 64KB + B-dbuf (BN*64*2*2B). Per K-tile: 4 phases {ds_read 2 mreps;
// stage one half-tile of t+1; s_barrier; setprio(1); MFMA cluster; setprio(0); s_barrier};
// ONE vmcnt(0) per tile, issued 4 phases after the loads (latency hidden). Raw barriers.
// MODE 0: Q|K  (BN=256, N=2048): SWAPPED mfma -> n-quad -> 8B stores [b][h][p][d]; Q*0.125.
// MODE 1: O    (BN=128, N=1024): SWAPPED -> n-quad -> 16B f32x4 stores [m][n].
// MODE 2: V    (BN=128, N=1024): NORMAL  -> m-quad (=p) -> 8B stores V^T [b][h][d][p].
// Grid all modes: dim3(8, 32) = 256 blocks = exactly 1/CU. Bijective XCD swizzle.
template<int MODE>
__global__ __launch_bounds__(512, 2) void gemm8(const short* __restrict__ A,
                                                const short* __restrict__ BT,
                                                const float* __restrict__ bias,
                                                const float* __restrict__ bias2,
                                                void* __restrict__ outp) {
    constexpr int BN = (MODE == 0) ? 256 : 128;
    constexpr int NREP = BN / 64;            // per-wave n-subtiles (wave covers BN/4)
    __shared__ __align__(16) short lA[2][256 * 64];
    __shared__ __align__(16) short lB[2][BN * 64];
    const int tid = threadIdx.x;             // 0..511
    const int lane = tid & 63;
    const int w = tid >> 6;                  // 0..7
    const int wm = w >> 2, wn = w & 3;
    const int li = lane & 15, g = lane >> 4;

    const int flat = blockIdx.y * 8 + blockIdx.x;
    const int lid = (flat & 7) * 32 + (flat >> 3);
    const int m0 = (lid >> 3) * 256;
    const int n0 = (lid & 7) * BN;

    // staging map: 16B unit e of a [128][64] half-tile: row=e>>3, logical u=(e&7)^(row&7)
    const int e0 = tid, e1 = tid + 512;
    const int r0 = e0 >> 3, lu0 = (e0 & 7) ^ (r0 & 7);
    const int r1 = e1 >> 3, lu1 = (e1 & 7) ^ (r1 & 7);
    const short* aS0 = A + (size_t)(m0 + r0) * K_DIM + lu0 * 8;
    const short* aS1 = A + (size_t)(m0 + r1) * K_DIM + lu1 * 8;
    const short* bS0 = BT + (size_t)(n0 + r0) * K_DIM + lu0 * 8;
    const short* bS1 = BT + (size_t)(n0 + r1) * K_DIM + lu1 * 8;
    const int dA0 = e0 * 8, dA1 = e1 * 8;
    const int dB0 = dA0, dB1 = dA1;

#define STAGE_A8(buf, hh, kt) do { \
    GLDS16(aS0 + (size_t)(hh) * 128 * K_DIM + (kt) * 64, &lA[buf][(hh) * 8192 + dA0]); \
    GLDS16(aS1 + (size_t)(hh) * 128 * K_DIM + (kt) * 64, &lA[buf][(hh) * 8192 + dA1]); } while (0)
#define STAGE_B8(buf, hh, kt) do { \
    GLDS16(bS0 + (size_t)(hh) * 128 * K_DIM + (kt) * 64, &lB[buf][(hh) * 8192 + dB0]); \
    GLDS16(bS1 + (size_t)(hh) * 128 * K_DIM + (kt) * 64, &lB[buf][(hh) * 8192 + dB1]); } while (0)

    // fragment offsets (swizzled): off(row, u) = row*64 + (u^(row&7))*8, u = ks*4+g
    int aoff[8][2], boff[NREP][2];
#pragma unroll
    for (int mrep = 0; mrep < 8; ++mrep) {
        const int row = wm * 128 + mrep * 16 + li;
#pragma unroll
        for (int ks = 0; ks < 2; ++ks)
            aoff[mrep][ks] = row * 64 + (((ks * 4 + g) ^ (row & 7)) * 8);
    }
#pragma unroll
    for (int nrep = 0; nrep < NREP; ++nrep) {
        const int row = wn * (BN / 4) + nrep * 16 + li;
#pragma unroll
        for (int ks = 0; ks < 2; ++ks)
            boff[nrep][ks] = row * 64 + (((ks * 4 + g) ^ (row & 7)) * 8);
    }

    f32x4 acc[8][NREP] = {};

    // prologue: stage tile 0 fully, drain, sync
    STAGE_A8(0, 0, 0); STAGE_A8(0, 1, 0);
    STAGE_B8(0, 0, 0);
    if (MODE == 0) STAGE_B8(0, 1, 0);
    asm volatile("s_waitcnt vmcnt(0)" ::: "memory");
    __builtin_amdgcn_s_barrier();

    for (int t = 0; t < 16; ++t) {
        const int buf = t & 1;
        const short* LA = lA[buf];
        const short* LB = lB[buf];
        bf16x8 bf[NREP][2];
#pragma unroll
        for (int p = 0; p < 4; ++p) {
            if (p == 0) {
#pragma unroll
                for (int nrep = 0; nrep < NREP; ++nrep)
#pragma unroll
                    for (int ks = 0; ks < 2; ++ks)
                        bf[nrep][ks] = *(const bf16x8*)&LB[boff[nrep][ks]];
            }
            bf16x8 af2[2][2];
#pragma unroll
            for (int i = 0; i < 2; ++i)
#pragma unroll
                for (int ks = 0; ks < 2; ++ks)
                    af2[i][ks] = *(const bf16x8*)&LA[aoff[2 * p + i][ks]];
            if (t < 15) {                    // stage one half-tile of t+1 per phase
                if (p == 0)      STAGE_A8(buf ^ 1, 0, t + 1);
                else if (p == 1) STAGE_A8(buf ^ 1, 1, t + 1);
                else if (p == 2) STAGE_B8(buf ^ 1, 0, t + 1);
                else if (MODE == 0) STAGE_B8(buf ^ 1, 1, t + 1);
            }
            __builtin_amdgcn_s_barrier();
            __builtin_amdgcn_s_setprio(1);
#pragma unroll
            for (int ks = 0; ks < 2; ++ks)
#pragma unroll
                for (int i = 0; i < 2; ++i)
#pragma unroll
                    for (int j = 0; j < NREP; ++j) {
                        if (MODE == 2)
                            acc[2 * p + i][j] = __builtin_amdgcn_mfma_f32_16x16x32_bf16(
                                af2[i][ks], bf[j][ks], acc[2 * p + i][j], 0, 0, 0);
                        else
                            acc[2 * p + i][j] = __builtin_amdgcn_mfma_f32_16x16x32_bf16(
                                bf[j][ks], af2[i][ks], acc[2 * p + i][j], 0, 0, 0);
                    }
            __builtin_amdgcn_s_setprio(0);
            __builtin_amdgcn_s_barrier();
        }
        asm volatile("s_waitcnt vmcnt(0)" ::: "memory");   // t+1 fully landed
        __builtin_amdgcn_s_barrier();
    }

    if (MODE == 0) {
        // swapped D (row=n): n-quad -> 8B stores into heads layout; Q-scale on proj 0
#pragma unroll
        for (int nrep = 0; nrep < NREP; ++nrep) {
            const int nb = n0 + wn * 64 + nrep * 16 + 4 * g;
            const float* bp = nb < 1024 ? bias : bias2;
            const float sc = nb < 1024 ? 0.125f : 1.0f;
            const f32x4 bb = *(const f32x4*)&bp[nb & 1023];
            const int hI = (nb >> 6) & 15, d = nb & 63;
            short* base = (short*)outp + (size_t)(nb >> 10) * M_DIM * C_DIM;
#pragma unroll
            for (int mrep = 0; mrep < 8; ++mrep) {
                const int m = m0 + wm * 128 + mrep * 16 + li;
                const int bI = m >> 11, p = m & 2047;
                s16x4 v4;
#pragma unroll
                for (int r = 0; r < 4; ++r) v4[r] = f2bf((acc[mrep][nrep][r] + bb[r]) * sc);
                *(s16x4*)&base[(((size_t)bI * H_CNT + hI) * P_DIM + p) * D_HEAD + d] = v4;
            }
        }
    } else if (MODE == 1) {
        // swapped D: n-quad -> f32x4 stores [m][n]
#pragma unroll
        for (int nrep = 0; nrep < NREP; ++nrep) {
            const int nb = n0 + wn * 32 + nrep * 16 + 4 * g;
            const f32x4 bb = *(const f32x4*)&bias[nb];
#pragma unroll
            for (int mrep = 0; mrep < 8; ++mrep) {
                const int m = m0 + wm * 128 + mrep * 16 + li;
                f32x4 v;
#pragma unroll
                for (int r = 0; r < 4; ++r) v[r] = acc[mrep][nrep][r] + bb[r];
                *(f32x4*)&((float*)outp)[(size_t)m * C_DIM + nb] = v;
            }
        }
    } else {
        // normal D (row=m): m-quad = consecutive p -> 8B stores into V^T [b][h][d][p]
#pragma unroll
        for (int nrep = 0; nrep < NREP; ++nrep) {
            const int n = n0 + wn * 32 + nrep * 16 + li;
            const float bb = bias[n];
            const int hI = n >> 6, d = n & 63;
#pragma unroll
            for (int mrep = 0; mrep < 8; ++mrep) {
                const int pbse = m0 + wm * 128 + mrep * 16 + 4 * g;
                const int bI = pbse >> 11, p = pbse & 2047;
                s16x4 v4;
#pragma unroll
                for (int r = 0; r < 4; ++r) v4[r] = f2bf(acc[mrep][nrep][r] + bb);
                *(s16x4*)&((short*)outp)[(((size_t)bI * H_CNT + hI) * D_HEAD + d) * P_DIM + p] = v4;
            }
        }
    }
#undef STAGE_A8
#undef STAGE_B8
}

// ---------------- flash attention — R14/R16 structure (frozen, 90.3us measured) ----------------
__global__ __launch_bounds__(256, 4) void attn_fwd(const short* __restrict__ Q,
                                                   const short* __restrict__ Kb,
                                                   const short* __restrict__ VT,
                                                   short* __restrict__ Y) {
    const int flat = blockIdx.y * 16 + blockIdx.x;
    const int xcd = flat & 7, rr = flat >> 3;
    const int bh = xcd + 8 * (rr >> 4);
    const int qx = rr & 15;

    const int b = bh >> 4, h = bh & 15;
    const int tid = threadIdx.x;
    const int w = tid >> 6, lane = tid & 63;
    const int li = lane & 15, g = lane >> 4;
    const int x7 = li & 7;
    const int q0 = qx * 128 + w * 32;
    const short* Qh = Q + (size_t)bh * P_DIM * D_HEAD;
    const short* Kh = Kb + (size_t)bh * P_DIM * D_HEAD;
    const short* Vh = VT + (size_t)bh * D_HEAD * P_DIM;

    __shared__ __align__(16) short lK[64 * 64];
    __shared__ __align__(16) short lV[64 * 64];
    __shared__ __align__(16) short pb[4][32 * 64];
    short* pw = pb[w];

    bf16x8 qf[2][2];
#pragma unroll
    for (int qt = 0; qt < 2; ++qt)
#pragma unroll
        for (int c = 0; c < 2; ++c)
            qf[qt][c] = *(const bf16x8*)&Qh[(size_t)(q0 + qt * 16 + li) * D_HEAD + c * 32 + g * 8];

    f32x4 o[2][4] = {};
    float ps[2] = {};

    const int t1 = tid + 256;
    const int r0 = tid >> 3, u0 = (tid & 7) ^ (r0 & 7);
    const int r1 = t1 >> 3,  u1 = (t1 & 7) ^ (r1 & 7);
    const short* ks0 = Kh + r0 * D_HEAD + u0 * 8;
    const short* ks1 = Kh + r1 * D_HEAD + u1 * 8;
    const short* vs0 = Vh + r0 * P_DIM + u0 * 8;
    const short* vs1 = Vh + r1 * P_DIM + u1 * 8;
    short* dk0 = lK + tid * 8;  short* dk1 = lK + t1 * 8;
    short* dv0 = lV + tid * 8;  short* dv1 = lV + t1 * 8;

    const int pwrow0 = li * 64;
    const int wsw = x7 << 1;

    for (int k0 = 0; k0 < P_DIM; k0 += 64) {
        __syncthreads();
        GLDS16(ks0 + (size_t)k0 * D_HEAD, dk0);
        GLDS16(ks1 + (size_t)k0 * D_HEAD, dk1);
        GLDS16(vs0 + k0, dv0);
        GLDS16(vs1 + k0, dv1);
        __syncthreads();

        bf16x8 kf[4][2];
#pragma unroll
        for (int kt = 0; kt < 4; ++kt) {
            const int rbase = (kt * 16 + li) * 64;
            kf[kt][0] = *(const bf16x8*)&lK[rbase + ((0 + g) ^ x7) * 8];
            kf[kt][1] = *(const bf16x8*)&lK[rbase + ((4 + g) ^ x7) * 8];
        }

#pragma unroll
        for (int qt = 0; qt < 2; ++qt) {
            f32x4 s[4] = {};
#pragma unroll
            for (int kt = 0; kt < 4; ++kt) {
                s[kt] = __builtin_amdgcn_mfma_f32_16x16x32_bf16(kf[kt][0], qf[qt][0], s[kt], 0, 0, 0);
                s[kt] = __builtin_amdgcn_mfma_f32_16x16x32_bf16(kf[kt][1], qf[qt][1], s[kt], 0, 0, 0);
            }
            const int rowb = pwrow0 + qt * 16 * 64;
#pragma unroll
            for (int kt = 0; kt < 4; ++kt) {
                bf16x4 pv4;
#pragma unroll
                for (int r = 0; r < 4; ++r) {
                    float e = __expf(s[kt][r]);
                    ps[qt] += e;
                    pv4[r] = (__bf16)e;
                }
                const int j = (kt * 4 + g) ^ wsw;
                *(bf16x4*)&pw[rowb + j * 4] = pv4;
            }
        }
        __builtin_amdgcn_sched_barrier(0);
        asm volatile("s_waitcnt lgkmcnt(0)" ::: "memory");
        __builtin_amdgcn_sched_barrier(0);
#pragma unroll
        for (int kc = 0; kc < 2; ++kc) {
            bf16x8 pf[2];
#pragma unroll
            for (int qt = 0; qt < 2; ++qt) {
                const int j = (8 * kc + 2 * g) ^ wsw;
                pf[qt] = *(const bf16x8*)&pw[(qt * 16 + li) * 64 + j * 4];
            }
#pragma unroll
            for (int dt = 0; dt < 4; ++dt) {
                bf16x8 vf = *(const bf16x8*)&lV[(dt * 16 + li) * 64 + ((kc * 4 + g) ^ x7) * 8];
                o[0][dt] = __builtin_amdgcn_mfma_f32_16x16x32_bf16(pf[0], vf, o[0][dt], 0, 0, 0);
                o[1][dt] = __builtin_amdgcn_mfma_f32_16x16x32_bf16(pf[1], vf, o[1][dt], 0, 0, 0);
            }
        }
    }

#pragma unroll
    for (int qt = 0; qt < 2; ++qt) {
        float v = ps[qt];
        v += __shfl_xor(v, 16);
        v += __shfl_xor(v, 32);
#pragma unroll
        for (int r = 0; r < 4; ++r) {
            const float inv = 1.0f / __shfl(v, 4 * g + r);
            const int p = q0 + qt * 16 + 4 * g + r;
            short* yrow = Y + ((size_t)b * P_DIM + p) * C_DIM + h * D_HEAD;
#pragma unroll
            for (int dt = 0; dt < 4; ++dt)
                yrow[dt * 16 + li] = f2bf(o[qt][dt][r] * inv);
        }
    }
}

extern "C" void kernel_launch(void* const* d_in, const int* in_sizes, int n_in,
                              void* d_out, int out_size, void* d_ws, size_t ws_size,
                              hipStream_t stream) {
    (void)in_sizes; (void)n_in; (void)out_size; (void)ws_size;
    const float* x  = (const float*)d_in[0];
    const float* Wq = (const float*)d_in[1];
    const float* bq = (const float*)d_in[2];
    const float* Wk = (const float*)d_in[3];
    const float* bk = (const float*)d_in[4];
    const float* Wv = (const float*)d_in[5];
    const float* bv = (const float*)d_in[6];
    const float* Wo = (const float*)d_in[7];
    const float* bo = (const float*)d_in[8];

    short* ws  = (short*)d_ws;
    short* xb  = ws;                              // [8192][1024] bf16
    short* wqt = xb  + (size_t)M_DIM * C_DIM;     // [1024][1024] x4, contiguous [wq|wk|wv|wo]
    short* wvt = wqt + 2 * (size_t)C_DIM * C_DIM;
    short* wot = wqt + 3 * (size_t)C_DIM * C_DIM;
    short* qd  = wot + (size_t)C_DIM * C_DIM;     // [bh][p][d]; kd, vtd follow contiguously
    short* kd  = qd  + (size_t)M_DIM * C_DIM;
    short* vtd = kd  + (size_t)M_DIM * C_DIM;     // [bh][d][p]
    short* yd  = vtd + (size_t)M_DIM * C_DIM;     // [b][p][c]

    cvt_f32_bf16<<<dim3(M_DIM * C_DIM / 1024), 256, 0, stream>>>(x, xb);
    wtrans_all<<<dim3(32, 32, 4), 256, 0, stream>>>(Wq, Wk, Wv, Wo, wqt);
    // Q|K fused projection — 8-phase, BN=256 (Q pre-scaled by 1/8)
    gemm8<0><<<dim3(8, 32), 512, 0, stream>>>(xb, wqt, bq, bk, qd);
    // V projection -> V^T direct — 8-phase, BN=128, normal orientation
    gemm8<2><<<dim3(8, 32), 512, 0, stream>>>(xb, wvt, bv, nullptr, vtd);
    attn_fwd<<<dim3(16, 64), 256, 0, stream>>>(qd, kd, vtd, yd);
    // output projection — 8-phase, BN=128, swapped, f32x4 stores
    gemm8<1><<<dim3(8, 32), 512, 0, stream>>>(yd, wot, bo, nullptr, d_out);
}

// Round 19
// 194.466 us; speedup vs baseline: 1.0317x; 1.0317x over previous
//
#include <hip/hip_runtime.h>

#define B_DIM 4
#define P_DIM 2048
#define C_DIM 1024
#define H_CNT 16
#define D_HEAD 64
#define M_DIM 8192   // B*P
#define K_DIM 1024

typedef __attribute__((ext_vector_type(4))) float  f32x4;
typedef __attribute__((ext_vector_type(8))) __bf16 bf16x8;
typedef __attribute__((ext_vector_type(4))) __bf16 bf16x4;
typedef __attribute__((ext_vector_type(4))) short  s16x4;
typedef __attribute__((ext_vector_type(8))) short  s16x8;

static __device__ __forceinline__ short f2bf(float f) {
    unsigned u = __float_as_uint(f);
    u += 0x7fff + ((u >> 16) & 1);   // RNE
    return (short)(u >> 16);
}

#define GLDS16(src, dst) __builtin_amdgcn_global_load_lds( \
    (__attribute__((address_space(1))) void*)(void*)(src), \
    (__attribute__((address_space(3))) void*)(void*)(dst), 16, 0, 0)

// ---------------- f32 -> bf16 elementwise (x) ----------------
__global__ __launch_bounds__(256) void cvt_f32_bf16(const float* __restrict__ in,
                                                    short* __restrict__ out) {
    size_t i = ((size_t)blockIdx.x * 256 + threadIdx.x) * 4;
    f32x4 v = *(const f32x4*)(in + i);
    s16x4 o;
    o[0] = f2bf(v[0]); o[1] = f2bf(v[1]); o[2] = f2bf(v[2]); o[3] = f2bf(v[3]);
    *(s16x4*)(out + i) = o;
}

// ---------------- all four W [K][N] f32 -> W^T [N][K] bf16, one dispatch ----------------
__global__ __launch_bounds__(256) void wtrans_all(const float* __restrict__ W0,
                                                  const float* __restrict__ W1,
                                                  const float* __restrict__ W2,
                                                  const float* __restrict__ W3,
                                                  short* __restrict__ WT) {
    __shared__ float t[32][33];
    const int z = blockIdx.z;
    const float* W = z == 0 ? W0 : z == 1 ? W1 : z == 2 ? W2 : W3;
    short* dst = WT + (size_t)z * C_DIM * C_DIM;
    const int k0 = blockIdx.y * 32, n0 = blockIdx.x * 32;
    const int tx = threadIdx.x & 31, ty = threadIdx.x >> 5;   // ty 0..7
#pragma unroll
    for (int j = 0; j < 4; ++j)
        t[ty + j * 8][tx] = W[(size_t)(k0 + ty + j * 8) * C_DIM + n0 + tx];
    __syncthreads();
#pragma unroll
    for (int j = 0; j < 4; ++j)
        dst[(size_t)(n0 + ty + j * 8) * C_DIM + k0 + tx] = f2bf(t[tx][ty + j * 8]);
}

// ---------------- 8-phase 256^2 GEMM for the Q|K projection (R17, measured best) ----------------
// C[M=8192, N=2048] = A[M,K=1024] @ B, BT pre-transposed [N][K]. 512 threads = 8 waves
// (2M x 4N), per-wave output 128x64, BK=64, LDS 128KB (A,B double-buffered 256x64 tiles).
// Per K-tile: 4 phases {ds_read frags; stage 2 glds of tile t+1; s_barrier; setprio(1);
// 16 MFMA; setprio(0); s_barrier}; ONE vmcnt(0) per tile, issued 4 phases after the loads.
// NOTE (R18): this template pays ONLY at BN=256 geometry; BN=128 variants regressed
// (empty stage phase + 8-MFMA clusters vs same barrier count) — V/O stay on the 128^2 kernel.
__global__ __launch_bounds__(512, 2) void gemm_qk8(const short* __restrict__ A,
                                                   const short* __restrict__ BT,
                                                   const float* __restrict__ bias,
                                                   const float* __restrict__ bias2,
                                                   short* __restrict__ outp) {
    __shared__ __align__(16) short lA[2][256 * 64];
    __shared__ __align__(16) short lB[2][256 * 64];
    const int tid = threadIdx.x;             // 0..511
    const int lane = tid & 63;
    const int w = tid >> 6;                  // 0..7
    const int wm = w >> 2, wn = w & 3;
    const int li = lane & 15, g = lane >> 4;

    const int flat = blockIdx.y * 8 + blockIdx.x;
    const int lid = (flat & 7) * 32 + (flat >> 3);
    const int m0 = (lid >> 3) * 256;
    const int n0 = (lid & 7) * 256;

    const int e0 = tid, e1 = tid + 512;
    const int r0 = e0 >> 3, lu0 = (e0 & 7) ^ (r0 & 7);
    const int r1 = e1 >> 3, lu1 = (e1 & 7) ^ (r1 & 7);
    const short* aS0 = A + (size_t)(m0 + r0) * K_DIM + lu0 * 8;
    const short* aS1 = A + (size_t)(m0 + r1) * K_DIM + lu1 * 8;
    const short* bS0 = BT + (size_t)(n0 + r0) * K_DIM + lu0 * 8;
    const short* bS1 = BT + (size_t)(n0 + r1) * K_DIM + lu1 * 8;
    const int dA0 = e0 * 8, dA1 = e1 * 8;
    const int dB0 = dA0, dB1 = dA1;

#define STAGE_A8(buf, hh, kt) do { \
    GLDS16(aS0 + (size_t)(hh) * 128 * K_DIM + (kt) * 64, &lA[buf][(hh) * 8192 + dA0]); \
    GLDS16(aS1 + (size_t)(hh) * 128 * K_DIM + (kt) * 64, &lA[buf][(hh) * 8192 + dA1]); } while (0)
#define STAGE_B8(buf, hh, kt) do { \
    GLDS16(bS0 + (size_t)(hh) * 128 * K_DIM + (kt) * 64, &lB[buf][(hh) * 8192 + dB0]); \
    GLDS16(bS1 + (size_t)(hh) * 128 * K_DIM + (kt) * 64, &lB[buf][(hh) * 8192 + dB1]); } while (0)

    int aoff[8][2], boff[4][2];
#pragma unroll
    for (int mrep = 0; mrep < 8; ++mrep) {
        const int row = wm * 128 + mrep * 16 + li;
#pragma unroll
        for (int ks = 0; ks < 2; ++ks)
            aoff[mrep][ks] = row * 64 + (((ks * 4 + g) ^ (row & 7)) * 8);
    }
#pragma unroll
    for (int nrep = 0; nrep < 4; ++nrep) {
        const int row = wn * 64 + nrep * 16 + li;
#pragma unroll
        for (int ks = 0; ks < 2; ++ks)
            boff[nrep][ks] = row * 64 + (((ks * 4 + g) ^ (row & 7)) * 8);
    }

    f32x4 acc[8][4] = {};

    STAGE_A8(0, 0, 0); STAGE_A8(0, 1, 0);
    STAGE_B8(0, 0, 0); STAGE_B8(0, 1, 0);
    asm volatile("s_waitcnt vmcnt(0)" ::: "memory");
    __builtin_amdgcn_s_barrier();

    for (int t = 0; t < 16; ++t) {
        const int buf = t & 1;
        const short* LA = lA[buf];
        const short* LB = lB[buf];
        bf16x8 bf[4][2];
#pragma unroll
        for (int p = 0; p < 4; ++p) {
            if (p == 0) {
#pragma unroll
                for (int nrep = 0; nrep < 4; ++nrep)
#pragma unroll
                    for (int ks = 0; ks < 2; ++ks)
                        bf[nrep][ks] = *(const bf16x8*)&LB[boff[nrep][ks]];
            }
            bf16x8 af2[2][2];
#pragma unroll
            for (int i = 0; i < 2; ++i)
#pragma unroll
                for (int ks = 0; ks < 2; ++ks)
                    af2[i][ks] = *(const bf16x8*)&LA[aoff[2 * p + i][ks]];
            if (t < 15) {
                if (p == 0)      STAGE_A8(buf ^ 1, 0, t + 1);
                else if (p == 1) STAGE_A8(buf ^ 1, 1, t + 1);
                else if (p == 2) STAGE_B8(buf ^ 1, 0, t + 1);
                else             STAGE_B8(buf ^ 1, 1, t + 1);
            }
            __builtin_amdgcn_s_barrier();
            __builtin_amdgcn_s_setprio(1);
#pragma unroll
            for (int ks = 0; ks < 2; ++ks)
#pragma unroll
                for (int i = 0; i < 2; ++i)
#pragma unroll
                    for (int j = 0; j < 4; ++j)
                        acc[2 * p + i][j] = __builtin_amdgcn_mfma_f32_16x16x32_bf16(
                            bf[j][ks], af2[i][ks], acc[2 * p + i][j], 0, 0, 0);
            __builtin_amdgcn_s_setprio(0);
            __builtin_amdgcn_s_barrier();
        }
        asm volatile("s_waitcnt vmcnt(0)" ::: "memory");
        __builtin_amdgcn_s_barrier();
    }

#pragma unroll
    for (int nrep = 0; nrep < 4; ++nrep) {
        const int nb = n0 + wn * 64 + nrep * 16 + 4 * g;
        const float* bp = nb < 1024 ? bias : bias2;
        const float sc = nb < 1024 ? 0.125f : 1.0f;
        const f32x4 bb = *(const f32x4*)&bp[nb & 1023];
        const int hI = (nb >> 6) & 15, d = nb & 63;
        short* base = outp + (size_t)(nb >> 10) * M_DIM * C_DIM;
#pragma unroll
        for (int mrep = 0; mrep < 8; ++mrep) {
            const int m = m0 + wm * 128 + mrep * 16 + li;
            const int bI = m >> 11, p = m & 2047;
            s16x4 v4;
#pragma unroll
            for (int r = 0; r < 4; ++r) v4[r] = f2bf((acc[mrep][nrep][r] + bb[r]) * sc);
            *(s16x4*)&base[(((size_t)bI * H_CNT + hI) * P_DIM + p) * D_HEAD + d] = v4;
        }
    }
#undef STAGE_A8
#undef STAGE_B8
}

// ---------------- 128^2 GEMM (best structure for N=1024 shapes, R10/R11 measured) ----------------
// MODE 1: output projection, SWAPPED -> 16B f32x4 stores.
// MODE 2: V (N=1024), NORMAL -> 8B stores to V^T [b][h][d][p].
// Bijective XCD swizzle (nwg % 8 == 0).
template<int MODE>
__global__ __launch_bounds__(256) void gemm_bt(const short* __restrict__ A,
                                               const short* __restrict__ BT,
                                               const float* __restrict__ bias,
                                               const float* __restrict__ bias2,
                                               void* __restrict__ outp,
                                               int gx) {
    const int h = blockIdx.y * gx + blockIdx.x;
    const int cpx = (gx << 6) >> 3;          // nwg/8
    const int lid = (h & 7) * cpx + (h >> 3);
    const int m0 = (lid / gx) * 128;
    const int n0 = (lid % gx) * 128;

    __shared__ __align__(16) short lA[128 * 32];
    __shared__ __align__(16) short lB[128 * 32];
    const int tid = threadIdx.x;
    const int lane = tid & 63;
    const int w = tid >> 6;
    const int wr = (w >> 1) * 64;
    const int wc = (w & 1) * 64;
    const int li = lane & 15, g = lane >> 4;

    f32x4 acc[4][4] = {};

    const int r0s = tid >> 2, r1s = (tid + 256) >> 2;
    const int c0 = (tid & 3) ^ ((r0s >> 1) & 3);
    const int c1 = (tid & 3) ^ ((r1s >> 1) & 3);
    const short* a0 = A + (size_t)(m0 + r0s) * K_DIM + c0 * 8;
    const short* a1 = A + (size_t)(m0 + r1s) * K_DIM + c1 * 8;
    const short* b0 = BT + (size_t)(n0 + r0s) * K_DIM + c0 * 8;
    const short* b1 = BT + (size_t)(n0 + r1s) * K_DIM + c1 * 8;
    short* lA0 = lA + w * 512;  short* lA1 = lA + 2048 + w * 512;
    short* lB0 = lB + w * 512;  short* lB1 = lB + 2048 + w * 512;

    int aoff[4], boff[4];
#pragma unroll
    for (int i = 0; i < 4; ++i) {
        int ra = wr + i * 16 + li;  int pa = g ^ ((ra >> 1) & 3);
        aoff[i] = ra * 32 + pa * 8;
        int rb = wc + i * 16 + li;  int pb = g ^ ((rb >> 1) & 3);
        boff[i] = rb * 32 + pb * 8;
    }

    for (int k0 = 0; k0 < K_DIM; k0 += 32) {
        __syncthreads();
        GLDS16(a0 + k0, lA0);
        GLDS16(a1 + k0, lA1);
        GLDS16(b0 + k0, lB0);
        GLDS16(b1 + k0, lB1);
        __syncthreads();
        bf16x8 af[4], bfr[4];
#pragma unroll
        for (int i = 0; i < 4; ++i) {
            af[i]  = *(const bf16x8*)&lA[aoff[i]];
            bfr[i] = *(const bf16x8*)&lB[boff[i]];
        }
#pragma unroll
        for (int i = 0; i < 4; ++i)
#pragma unroll
            for (int j = 0; j < 4; ++j) {
                if (MODE == 2)
                    acc[i][j] = __builtin_amdgcn_mfma_f32_16x16x32_bf16(
                        af[i], bfr[j], acc[i][j], 0, 0, 0);
                else
                    acc[i][j] = __builtin_amdgcn_mfma_f32_16x16x32_bf16(
                        bfr[j], af[i], acc[i][j], 0, 0, 0);
            }
    }

    if (MODE == 1) {
#pragma unroll
        for (int j = 0; j < 4; ++j) {
            const int nb = n0 + wc + j * 16 + 4 * g;
            const f32x4 bb = *(const f32x4*)&bias[nb];
#pragma unroll
            for (int i = 0; i < 4; ++i) {
                const int m = m0 + wr + i * 16 + li;
                f32x4 v;
#pragma unroll
                for (int r = 0; r < 4; ++r) v[r] = acc[i][j][r] + bb[r];
                *(f32x4*)&((float*)outp)[(size_t)m * C_DIM + nb] = v;
            }
        }
    } else {
#pragma unroll
        for (int j = 0; j < 4; ++j) {
            const int nn = n0 + wc + j * 16 + li;
            const float bb = bias[nn];
            const int hI = nn >> 6, d = nn & 63;
#pragma unroll
            for (int i = 0; i < 4; ++i) {
                const int pbse = m0 + wr + i * 16 + 4 * g;
                const int bI = pbse >> 11, p = pbse & 2047;
                s16x4 v4;
#pragma unroll
                for (int r = 0; r < 4; ++r) v4[r] = f2bf(acc[i][j][r] + bb);
                *(s16x4*)&((short*)outp)[(((size_t)bI * H_CNT + hI) * D_HEAD + d) * P_DIM + p] = v4;
            }
        }
    }
}

// ---------------- flash attention — frozen structure (90.3us measured, R14/R16) ----------------
// Structure floor established by four independent null experiments: bank conflicts (R13),
// HBM traffic (R14: FETCH 139->25MB, flat), LDS-bytes/q (R15), occupancy (R16).
__global__ __launch_bounds__(256, 4) void attn_fwd(const short* __restrict__ Q,
                                                   const short* __restrict__ Kb,
                                                   const short* __restrict__ VT,
                                                   short* __restrict__ Y) {
    const int flat = blockIdx.y * 16 + blockIdx.x;
    const int xcd = flat & 7, rr = flat >> 3;
    const int bh = xcd + 8 * (rr >> 4);
    const int qx = rr & 15;

    const int b = bh >> 4, h = bh & 15;
    const int tid = threadIdx.x;
    const int w = tid >> 6, lane = tid & 63;
    const int li = lane & 15, g = lane >> 4;
    const int x7 = li & 7;
    const int q0 = qx * 128 + w * 32;
    const short* Qh = Q + (size_t)bh * P_DIM * D_HEAD;
    const short* Kh = Kb + (size_t)bh * P_DIM * D_HEAD;
    const short* Vh = VT + (size_t)bh * D_HEAD * P_DIM;

    __shared__ __align__(16) short lK[64 * 64];
    __shared__ __align__(16) short lV[64 * 64];
    __shared__ __align__(16) short pb[4][32 * 64];
    short* pw = pb[w];

    bf16x8 qf[2][2];
#pragma unroll
    for (int qt = 0; qt < 2; ++qt)
#pragma unroll
        for (int c = 0; c < 2; ++c)
            qf[qt][c] = *(const bf16x8*)&Qh[(size_t)(q0 + qt * 16 + li) * D_HEAD + c * 32 + g * 8];

    f32x4 o[2][4] = {};
    float ps[2] = {};

    const int t1 = tid + 256;
    const int r0 = tid >> 3, u0 = (tid & 7) ^ (r0 & 7);
    const int r1 = t1 >> 3,  u1 = (t1 & 7) ^ (r1 & 7);
    const short* ks0 = Kh + r0 * D_HEAD + u0 * 8;
    const short* ks1 = Kh + r1 * D_HEAD + u1 * 8;
    const short* vs0 = Vh + r0 * P_DIM + u0 * 8;
    const short* vs1 = Vh + r1 * P_DIM + u1 * 8;
    short* dk0 = lK + tid * 8;  short* dk1 = lK + t1 * 8;
    short* dv0 = lV + tid * 8;  short* dv1 = lV + t1 * 8;

    const int pwrow0 = li * 64;
    const int wsw = x7 << 1;

    for (int k0 = 0; k0 < P_DIM; k0 += 64) {
        __syncthreads();
        GLDS16(ks0 + (size_t)k0 * D_HEAD, dk0);
        GLDS16(ks1 + (size_t)k0 * D_HEAD, dk1);
        GLDS16(vs0 + k0, dv0);
        GLDS16(vs1 + k0, dv1);
        __syncthreads();

        bf16x8 kf[4][2];
#pragma unroll
        for (int kt = 0; kt < 4; ++kt) {
            const int rbase = (kt * 16 + li) * 64;
            kf[kt][0] = *(const bf16x8*)&lK[rbase + ((0 + g) ^ x7) * 8];
            kf[kt][1] = *(const bf16x8*)&lK[rbase + ((4 + g) ^ x7) * 8];
        }

#pragma unroll
        for (int qt = 0; qt < 2; ++qt) {
            f32x4 s[4] = {};
#pragma unroll
            for (int kt = 0; kt < 4; ++kt) {
                s[kt] = __builtin_amdgcn_mfma_f32_16x16x32_bf16(kf[kt][0], qf[qt][0], s[kt], 0, 0, 0);
                s[kt] = __builtin_amdgcn_mfma_f32_16x16x32_bf16(kf[kt][1], qf[qt][1], s[kt], 0, 0, 0);
            }
            const int rowb = pwrow0 + qt * 16 * 64;
#pragma unroll
            for (int kt = 0; kt < 4; ++kt) {
                bf16x4 pv4;
#pragma unroll
                for (int r = 0; r < 4; ++r) {
                    float e = __expf(s[kt][r]);
                    ps[qt] += e;
                    pv4[r] = (__bf16)e;
                }
                const int j = (kt * 4 + g) ^ wsw;
                *(bf16x4*)&pw[rowb + j * 4] = pv4;
            }
        }
        __builtin_amdgcn_sched_barrier(0);
        asm volatile("s_waitcnt lgkmcnt(0)" ::: "memory");
        __builtin_amdgcn_sched_barrier(0);
#pragma unroll
        for (int kc = 0; kc < 2; ++kc) {
            bf16x8 pf[2];
#pragma unroll
            for (int qt = 0; qt < 2; ++qt) {
                const int j = (8 * kc + 2 * g) ^ wsw;
                pf[qt] = *(const bf16x8*)&pw[(qt * 16 + li) * 64 + j * 4];
            }
#pragma unroll
            for (int dt = 0; dt < 4; ++dt) {
                bf16x8 vf = *(const bf16x8*)&lV[(dt * 16 + li) * 64 + ((kc * 4 + g) ^ x7) * 8];
                o[0][dt] = __builtin_amdgcn_mfma_f32_16x16x32_bf16(pf[0], vf, o[0][dt], 0, 0, 0);
                o[1][dt] = __builtin_amdgcn_mfma_f32_16x16x32_bf16(pf[1], vf, o[1][dt], 0, 0, 0);
            }
        }
    }

#pragma unroll
    for (int qt = 0; qt < 2; ++qt) {
        float v = ps[qt];
        v += __shfl_xor(v, 16);
        v += __shfl_xor(v, 32);
#pragma unroll
        for (int r = 0; r < 4; ++r) {
            const float inv = 1.0f / __shfl(v, 4 * g + r);
            const int p = q0 + qt * 16 + 4 * g + r;
            short* yrow = Y + ((size_t)b * P_DIM + p) * C_DIM + h * D_HEAD;
#pragma unroll
            for (int dt = 0; dt < 4; ++dt)
                yrow[dt * 16 + li] = f2bf(o[qt][dt][r] * inv);
        }
    }
}

extern "C" void kernel_launch(void* const* d_in, const int* in_sizes, int n_in,
                              void* d_out, int out_size, void* d_ws, size_t ws_size,
                              hipStream_t stream) {
    (void)in_sizes; (void)n_in; (void)out_size; (void)ws_size;
    const float* x  = (const float*)d_in[0];
    const float* Wq = (const float*)d_in[1];
    const float* bq = (const float*)d_in[2];
    const float* Wk = (const float*)d_in[3];
    const float* bk = (const float*)d_in[4];
    const float* Wv = (const float*)d_in[5];
    const float* bv = (const float*)d_in[6];
    const float* Wo = (const float*)d_in[7];
    const float* bo = (const float*)d_in[8];

    short* ws  = (short*)d_ws;
    short* xb  = ws;                              // [8192][1024] bf16
    short* wqt = xb  + (size_t)M_DIM * C_DIM;     // [1024][1024] x4, contiguous [wq|wk|wv|wo]
    short* wvt = wqt + 2 * (size_t)C_DIM * C_DIM;
    short* wot = wqt + 3 * (size_t)C_DIM * C_DIM;
    short* qd  = wot + (size_t)C_DIM * C_DIM;     // [bh][p][d]; kd, vtd follow contiguously
    short* kd  = qd  + (size_t)M_DIM * C_DIM;
    short* vtd = kd  + (size_t)M_DIM * C_DIM;     // [bh][d][p]
    short* yd  = vtd + (size_t)M_DIM * C_DIM;     // [b][p][c]

    cvt_f32_bf16<<<dim3(M_DIM * C_DIM / 1024), 256, 0, stream>>>(x, xb);
    wtrans_all<<<dim3(32, 32, 4), 256, 0, stream>>>(Wq, Wk, Wv, Wo, wqt);
    // Q|K fused projection — 8-phase 256^2 template (N=2048, Q pre-scaled by 1/8)
    gemm_qk8<<<dim3(8, 32), 512, 0, stream>>>(xb, wqt, bq, bk, qd);
    // V projection -> V^T direct — 128^2 structure (best for N=1024, R18 confirmed)
    gemm_bt<2><<<dim3(8, 64), 256, 0, stream>>>(xb, wvt, bv, nullptr, (void*)vtd, 8);
    attn_fwd<<<dim3(16, 64), 256, 0, stream>>>(qd, kd, vtd, yd);
    // output projection — 128^2 structure, swapped, f32x4 stores
    gemm_bt<1><<<dim3(8, 64), 256, 0, stream>>>(yd, wot, bo, nullptr, d_out, 8);
}